// Round 9
// baseline (331.298 us; speedup 1.0000x reference)
//
#include <hip/hip_runtime.h>
#include <cstdint>
#include <cstddef>

constexpr int T_ = 128;
constexpr int S_ = 512;
constexpr int B_ = 256;
constexpr int START_ = T_ - 3;  // 125
constexpr int STOP_  = T_ - 2;  // 126

// Barrier that only drains LDS (lgkmcnt), NOT vmcnt: global ph-stores and
// e-prefetch loads legally stay in flight across it (thread-private data).
__device__ __forceinline__ void lds_barrier() {
  asm volatile("s_waitcnt lgkmcnt(0)\n\ts_barrier" ::: "memory");
}

// readlane: wave-uniform lane index (SGPR) -> result lands in an SGPR.
__device__ __forceinline__ float readlane_f(float v, int sl) {
  return __int_as_float(__builtin_amdgcn_readlane(__float_as_int(v), sl));
}

// forced 3-input max (VOP3). Inputs are finite (no NaN in this problem):
// v_max3_f32(a,b,c) == fmaxf(fmaxf(a,b),c) bit-exactly.
__device__ __forceinline__ float max3f(float a, float b, float c) {
  float d;
  asm("v_max3_f32 %0, %1, %2, %3" : "=v"(d) : "v"(a), "v"(b), "v"(c));
  return d;
}

// max-reduce over the 8 ig-lanes (lane bits [0,3)) in pure row-DPP:
// quad xor1 (0xB1), quad xor2 (0x4E), row_half_mirror (0x141: reverses each
// 8-lane half; == xor4 once quad-uniform). All 8 lanes end with the max.
__device__ __forceinline__ float ig8_rmax(float m) {
  int x = __builtin_amdgcn_mov_dpp(__float_as_int(m), 0xB1, 0xF, 0xF, true);
  m = fmaxf(m, __int_as_float(x));
  x = __builtin_amdgcn_mov_dpp(__float_as_int(m), 0x4E, 0xF, 0xF, true);
  m = fmaxf(m, __int_as_float(x));
  x = __builtin_amdgcn_mov_dpp(__float_as_int(m), 0x141, 0xF, 0xF, true);
  m = fmaxf(m, __int_as_float(x));
  return m;
}

// padded part layout: value i at float offset i + 4*(i>>4).
// Thread ig's 16-float granule = floats [20ig, 20ig+16) (byte 80ig, 16B
// aligned). Quad-banks 20ig%32 = {0,20,8,28,16,4,24,12}+0..3: the 8 granule
// quads are disjoint and cover all 32 banks -> conflict-free; 8-fold
// same-address lane duplication is LDS broadcast (free).
__device__ __forceinline__ int pidx(int i) { return i + 4 * (i >> 4); }

// ---------------------------------------------------------------------------
// Forward: value-only Viterbi recursion, stores part_hist (S,B,T) fp32.
// FROZEN at the measured-best R8/R13 structure (199-203 us, 930 cyc/step).
// All experiments this round live in viterbi_trace.
// Bit-exact vs reference: max exactly associative, fl monotone =>
// max_i fl(fl(p+tr)+e) == fl(max_i fl(p+tr) + e).
// ---------------------------------------------------------------------------
__global__ __launch_bounds__(1024, 4) void viterbi_forward(
    const float* __restrict__ feats,   // (B,S,T)
    const float* __restrict__ trans,   // (T,T)
    float* __restrict__ ph)            // (S,B,T) workspace
{
  const int b    = blockIdx.x;
  const int tid  = threadIdx.x;
  const int lane = tid & 63;
  const int ig   = lane & 7;           // i-chunk: i in [16ig, 16ig+16)
  const int j    = tid >> 3;           // 0..127: this thread's output column

  __shared__ alignas(16) float part[2][160];

  // trans column j, rows 16ig..16ig+16 (16 VGPRs, fixed over t)
  float tc[16];
  #pragma unroll
  for (int ii = 0; ii < 16; ++ii)
    tc[ii] = trans[(16 * ig + ii) * T_ + j];

  const float* fb = feats + (size_t)b * S_ * T_;
  const int woff  = pidx(j);

  // t = 0: part0 = emit[0] + trans[START,:]
  float p0 = fb[j] + trans[START_ * T_ + j];
  if (ig == 0) {
    part[0][woff] = p0;
    ph[(size_t)b * T_ + j] = p0;
  }
  __syncthreads();

  auto stepf = [&](int t, float e) {
    const float4* p4 = (const float4*)part[(t - 1) & 1];
    float4 pa = p4[5 * ig];
    float4 pb = p4[5 * ig + 1];
    float4 pc = p4[5 * ig + 2];
    float4 pd = p4[5 * ig + 3];
    float a0  = pa.x + tc[0],  a1  = pa.y + tc[1],
          a2  = pa.z + tc[2],  a3  = pa.w + tc[3];
    float a4  = pb.x + tc[4],  a5  = pb.y + tc[5],
          a6  = pb.z + tc[6],  a7  = pb.w + tc[7];
    float a8  = pc.x + tc[8],  a9  = pc.y + tc[9],
          a10 = pc.z + tc[10], a11 = pc.w + tc[11];
    float a12 = pd.x + tc[12], a13 = pd.y + tc[13],
          a14 = pd.z + tc[14], a15 = pd.w + tc[15];
    float x0 = max3f(a0, a1, a2);
    float x1 = max3f(a3, a4, a5);
    float x2 = max3f(a6, a7, a8);
    float x3 = max3f(a9, a10, a11);
    float x4 = max3f(a12, a13, a14);
    float y0 = max3f(x0, x1, x2);
    float y1 = max3f(x3, x4, a15);
    float mm = fmaxf(y0, y1);
    mm = ig8_rmax(mm);                 // all 8 ig-lanes now hold max over i
    float np = mm + e;
    if (ig == 0) part[t & 1][woff] = np;
    lds_barrier();
    if (ig == 0)
      ph[((size_t)t * B_ + b) * T_ + j] = np;  // off critical path
  };

  // emission prefetch: 8 rows in flight (named A/B groups of 4, no rotation)
  float EA[4], EB[4];
  #pragma unroll
  for (int u = 0; u < 4; ++u)
    EA[u] = fb[(size_t)(1 + u) * T_ + j];

  for (int t0 = 1; t0 < S_; t0 += 8) {
    #pragma unroll
    for (int u = 0; u < 4; ++u) {
      int tr = t0 + 4 + u; if (tr > S_ - 1) tr = S_ - 1;
      EB[u] = fb[(size_t)tr * T_ + j];
    }
    #pragma unroll
    for (int u = 0; u < 4; ++u) { int t = t0 + u; if (t < S_) stepf(t, EA[u]); }
    #pragma unroll
    for (int u = 0; u < 4; ++u) {
      int tr = t0 + 8 + u; if (tr > S_ - 1) tr = S_ - 1;
      EA[u] = fb[(size_t)tr * T_ + j];
    }
    #pragma unroll
    for (int u = 0; u < 4; ++u) { int t = t0 + 4 + u; if (t < S_) stepf(t, EB[u]); }
  }
}

// ---------------------------------------------------------------------------
// Trace: one wave per b, grid 256. R16 CHANGE: MINIMAL SCALAR CHAIN.
// Re-derived model from R7 (pure-lookup, 410 cyc/step, ~25 ops) and R15
// (recompute, 590 cyc/step, ~35 ops): a 1-wave serial chain pays full dep
// LATENCY per hop (~6-10 cyc VALU/SALU, ~120 ds_read), not issue cost.
// So cut chain hops:
//  (a) single-ballot pointer: m = q0|q1 is provably nonzero (tg is the max
//      of the recomputed candidates -> a match always exists), so ONE
//      s_ff1_i32_b64 (forced SALU via asm) gives idx = ptr>>1; parity from
//      one bit-test of q0. Replaces ffsll x2 + min + sentinel selects.
//  (b) v_readlane dest = SGPR; tg/e selected via scalar cselect and consumed
//      as SGPR operands in the next v_cmp/v_add -- no VGPR round-trips.
//  (c) trc ds_read issued immediately after ptr resolves, BEFORE the
//      readlanes, so readlane work hides under LDS latency.
// Tie-break exactness: first set lane of (q0|q1) = lowest candidate lane;
// at that lane even-i (q0) wins over odd-i -> identical first-occurrence
// order to the reference jnp.argmax.
// ---------------------------------------------------------------------------
constexpr int CH_ = 8;   // chunk size (steps per buffer)
constexpr int TS_ = 130; // transT row stride (even: float2-aligned, 2-way ok)

__global__ __launch_bounds__(64, 1) void viterbi_trace(
    const float* __restrict__ feats,   // (B,S,T)
    const void*  __restrict__ mask,    // (B,S) dtype detected at runtime
    const float* __restrict__ trans,   // (T,T)
    const float* __restrict__ ph,      // (S,B,T)
    int* __restrict__ out)             // (B,S) int32
{
  const int b    = blockIdx.x;
  const int lane = threadIdx.x;

  __shared__ alignas(16) float transT[T_ * TS_];  // transT[j*TS+i] = trans[i][j]
  #pragma unroll 4
  for (int g = lane; g < T_ * T_; g += 64) {
    int i = g >> 7, jj = g & (T_ - 1);
    transT[jj * TS_ + i] = trans[g];
  }
  __syncthreads();

  // ---- sequence length (mask dtype: uint8 / float32 / int32) ----
  int len = 0;
  {
    const int w0 = *(const int*)mask;  // element (0,0) is always true
    if (w0 == 0x01010101) {
      const unsigned char* m = (const unsigned char*)mask + (size_t)b * S_;
      for (int s = lane; s < S_; s += 64) len += (m[s] != 0);
    } else if (w0 == 0x3F800000) {
      const float* m = (const float*)mask + (size_t)b * S_;
      for (int s = lane; s < S_; s += 64) len += (m[s] != 0.0f);
    } else {
      const int* m = (const int*)mask + (size_t)b * S_;
      for (int s = lane; s < S_; s += 64) len += (m[s] != 0);
    }
    #pragma unroll
    for (int o = 32; o > 0; o >>= 1) len += __shfl_xor(len, o);
  }
  len = __builtin_amdgcn_readfirstlane(len);
  const int lp = len - 1;              // last valid position (>= S/2-1)

  // ---- final pointer: first argmax_i(ph_lp[i] + trans[i][STOP]) ----
  const float2 L = *(const float2*)(ph + ((size_t)lp * B_ + b) * T_ + 2 * lane);
  float v0 = L.x + transT[STOP_ * TS_ + 2 * lane];
  float v1 = L.y + transT[STOP_ * TS_ + 2 * lane + 1];
  float mx = fmaxf(v0, v1);
  #pragma unroll
  for (int o = 32; o > 0; o >>= 1) mx = fmaxf(mx, __shfl_xor(mx, o));
  {
    unsigned long long g0 = __ballot(v0 == mx);
    unsigned long long g1 = __ballot(v1 == mx);
    unsigned long long gm = g0 | g1;   // nonzero: mx is one of v0/v1
    int fidx;
    asm("s_ff1_i32_b64 %0, %1" : "=s"(fidx) : "s"(gm));
    unsigned fbit = (unsigned)(g0 >> fidx) & 1u;
    int pointer = 2 * fidx + 1 - (int)fbit;

    // ---- masked tail: out[k]=0 for lp<k<S-1; out[S-1]=out[lp]=pointer ----
    for (int k = lp + 1 + lane; k <= S_ - 2; k += 64) out[b * S_ + k] = 0;
    if (lane == 0) {
      out[b * S_ + (S_ - 1)] = pointer;
      if (lp < S_ - 1) out[b * S_ + lp] = pointer;
    }

    // ---- chase k = lp-1 .. 0 ----
    int   ptr = pointer;                                      // SGPR-resident
    float tg  = readlane_f((ptr & 1) ? L.y : L.x, ptr >> 1);  // ph[lp][ptr]
    const float* fb = feats + (size_t)b * S_ * T_;
    const float2 FL = *(const float2*)(fb + (size_t)lp * T_ + 2 * lane);
    float e = readlane_f((ptr & 1) ? FL.y : FL.x, ptr >> 1);  // feats[lp][ptr]
    // pipelined transT row for the first chase step
    float2 trc = *(const float2*)(transT + ptr * TS_ + 2 * lane);

    float2 PA[CH_], FA[CH_], PB[CH_], FB[CH_];

    auto issue = [&](float2 (&P)[CH_], float2 (&F)[CH_], int k0) {
      #pragma unroll
      for (int s = 0; s < CH_; ++s) {
        int k = k0 - s; if (k < 0) k = 0;     // clamped slots never used
        P[s] = *(const float2*)(ph + ((size_t)k * B_ + b) * T_ + 2 * lane);
        F[s] = *(const float2*)(fb + (size_t)k * T_ + 2 * lane);
      }
    };
    auto process = [&](const float2 (&P)[CH_], const float2 (&F)[CH_], int k0) {
      unsigned long long packed = 0;
      int cnt = 0;
      #pragma unroll
      for (int s = 0; s < CH_; ++s) {
        const int k = k0 - s;
        if (k >= 0) {
          // candidates c_i = fl(fl(ph_k[i]+trans[i,ptr]) + e), i = 2l, 2l+1
          float cx = (P[s].x + trc.x) + e;
          float cy = (P[s].y + trc.y) + e;
          unsigned long long q0 = __ballot(cx == tg);
          unsigned long long q1 = __ballot(cy == tg);
          unsigned long long m  = q0 | q1;       // provably nonzero
          int idx;
          asm("s_ff1_i32_b64 %0, %1" : "=s"(idx) : "s"(m));
          const unsigned bt = (unsigned)(q0 >> idx) & 1u;  // 1 => even i wins
          ptr = 2 * idx + 1 - (int)bt;
          // issue next transT row ASAP; readlanes below hide its latency
          trc = *(const float2*)(transT + ptr * TS_ + 2 * lane);
          packed = (packed << 8) | (unsigned)ptr;
          ++cnt;
          // next step (k-1) targets ph_k[ptr], feats[k][ptr] -- all scalar
          float rx = readlane_f(P[s].x, idx);
          float ry = readlane_f(P[s].y, idx);
          tg = bt ? rx : ry;
          float fx = readlane_f(F[s].x, idx);
          float fy = readlane_f(F[s].y, idx);
          e = bt ? fx : fy;
        }
      }
      // flush: step s handled k = k0-s; its ptr is byte (cnt-1-s) of packed
      if (lane < cnt)
        out[b * S_ + (k0 - lane)] =
            (int)((packed >> (8 * (cnt - 1 - lane))) & 0xFFull);
    };

    issue(PA, FA, lp - 1);
    for (int k0 = lp - 1; k0 >= 0; k0 -= 2 * CH_) {
      issue(PB, FB, k0 - CH_);
      process(PA, FA, k0);
      issue(PA, FA, k0 - 2 * CH_);
      process(PB, FB, k0 - CH_);
    }
  }
}

extern "C" void kernel_launch(void* const* d_in, const int* in_sizes, int n_in,
                              void* d_out, int out_size, void* d_ws, size_t ws_size,
                              hipStream_t stream) {
  const float* feats = (const float*)d_in[0];   // (B,S,T) fp32
  const void*  mask  = d_in[1];                 // (B,S) bool-ish
  const float* trans = (const float*)d_in[2];   // (T,T) fp32
  float* ph = (float*)d_ws;                     // (S,B,T) fp32 = 64 MB
  int*   out = (int*)d_out;                     // (B,S) int32

  viterbi_forward<<<dim3(B_), dim3(1024), 0, stream>>>(feats, trans, ph);
  viterbi_trace  <<<dim3(B_), dim3(64), 0, stream>>>(feats, mask, trans, ph, out);
}